// Round 1
// baseline (2789.300 us; speedup 1.0000x reference)
//
#include <hip/hip_runtime.h>
#include <math.h>

// Problem constants (fixed by setup_inputs)
#define NN   20000   // nodes
#define DEG  32      // neighbors per node (row_splits is uniform arange*32)
#define DIN  70      // 2*3 + 64 concat features
#define DH   256     // hidden
#define DC   64      // channels
#define NT   512     // threads per block (8 waves)

__device__ __forceinline__ float gelu_exact(float v) {
    // jax.nn.gelu(approximate=False) = 0.5*v*(1+erf(v/sqrt(2)))
    return 0.5f * v * (1.0f + erff(v * 0.70710678118654752f));
}

__global__ __launch_bounds__(NT, 4)
void it_fused_kernel(const float* __restrict__ y,
                     const float* __restrict__ x,
                     const float* __restrict__ f_y,
                     const float* __restrict__ wq,
                     const int*   __restrict__ nbr,
                     const float* __restrict__ W1, const float* __restrict__ b1,
                     const float* __restrict__ W2, const float* __restrict__ b2,
                     const float* __restrict__ W3, const float* __restrict__ b3,
                     float* __restrict__ out)
{
    const int i = blockIdx.x;   // node id; edges [i*32, i*32+32)
    const int t = threadIdx.x;

    __shared__ float s_h1[DEG][DH];     // 32 KiB
    __shared__ float s_h2[DEG][DH];     // 32 KiB
    __shared__ int   s_nbr[DEG];
    __shared__ float s_wq[DEG];
    __shared__ union {
        float agg[DEG][72];             // input tile, padded 70->72
        float red[DEG][68];             // reduction buffer (reused after agg reads done)
    } su;                               // 9 KiB

    // ---- neighbor indices + quadrature weights (weights[nbr[e]]) ----
    if (t < DEG) {
        int n = nbr[i * DEG + t];
        s_nbr[t] = n;
        s_wq[t]  = wq[n];
    }
    __syncthreads();

    // ---- build agg tile: concat(y[nbr], x[i], f_y[nbr]) ----
    for (int idx = t; idx < DEG * DIN; idx += NT) {
        int e = idx / DIN;
        int c = idx - e * DIN;
        int n = s_nbr[e];
        float v;
        if (c < 3)       v = y[n * 3 + c];
        else if (c < 6)  v = x[i * 3 + (c - 3)];
        else             v = f_y[n * DC + (c - 6)];
        su.agg[e][c] = v;
    }
    __syncthreads();

    // ---- stage 1: h1 = gelu(agg @ W1 + b1)  [32x70 @ 70x256] ----
    {
        const int jg = t & 63;      // column group: j0 = jg*4
        const int eg = t >> 6;      // wave id 0..7 -> edges eg*4 .. +3
        const int j0 = jg * 4;
        const int e0 = eg * 4;
        float acc[4][4];
        float4 bv = *(const float4*)&b1[j0];
        #pragma unroll
        for (int e = 0; e < 4; ++e) {
            acc[e][0] = bv.x; acc[e][1] = bv.y; acc[e][2] = bv.z; acc[e][3] = bv.w;
        }
        for (int k = 0; k < DIN; ++k) {
            float4 w = *(const float4*)&W1[k * DH + j0];
            #pragma unroll
            for (int e = 0; e < 4; ++e) {
                float a = su.agg[e0 + e][k];   // wave-uniform -> LDS broadcast
                acc[e][0] = fmaf(a, w.x, acc[e][0]);
                acc[e][1] = fmaf(a, w.y, acc[e][1]);
                acc[e][2] = fmaf(a, w.z, acc[e][2]);
                acc[e][3] = fmaf(a, w.w, acc[e][3]);
            }
        }
        #pragma unroll
        for (int e = 0; e < 4; ++e) {
            float4 r;
            r.x = gelu_exact(acc[e][0]);
            r.y = gelu_exact(acc[e][1]);
            r.z = gelu_exact(acc[e][2]);
            r.w = gelu_exact(acc[e][3]);
            *(float4*)&s_h1[e0 + e][j0] = r;
        }
    }
    __syncthreads();

    // ---- stage 2: h2 = gelu(h1 @ W2 + b2)  [32x256 @ 256x256] ----
    {
        const int jg = t & 63;
        const int eg = t >> 6;
        const int j0 = jg * 4;
        const int e0 = eg * 4;
        float acc[4][4];
        float4 bv = *(const float4*)&b2[j0];
        #pragma unroll
        for (int e = 0; e < 4; ++e) {
            acc[e][0] = bv.x; acc[e][1] = bv.y; acc[e][2] = bv.z; acc[e][3] = bv.w;
        }
        for (int k = 0; k < DH; k += 4) {
            float4 w0 = *(const float4*)&W2[(k + 0) * DH + j0];
            float4 w1 = *(const float4*)&W2[(k + 1) * DH + j0];
            float4 w2 = *(const float4*)&W2[(k + 2) * DH + j0];
            float4 w3 = *(const float4*)&W2[(k + 3) * DH + j0];
            #pragma unroll
            for (int e = 0; e < 4; ++e) {
                float4 a = *(const float4*)&s_h1[e0 + e][k];   // wave-uniform b128
                acc[e][0] = fmaf(a.x, w0.x, acc[e][0]);
                acc[e][0] = fmaf(a.y, w1.x, acc[e][0]);
                acc[e][0] = fmaf(a.z, w2.x, acc[e][0]);
                acc[e][0] = fmaf(a.w, w3.x, acc[e][0]);
                acc[e][1] = fmaf(a.x, w0.y, acc[e][1]);
                acc[e][1] = fmaf(a.y, w1.y, acc[e][1]);
                acc[e][1] = fmaf(a.z, w2.y, acc[e][1]);
                acc[e][1] = fmaf(a.w, w3.y, acc[e][1]);
                acc[e][2] = fmaf(a.x, w0.z, acc[e][2]);
                acc[e][2] = fmaf(a.y, w1.z, acc[e][2]);
                acc[e][2] = fmaf(a.z, w2.z, acc[e][2]);
                acc[e][2] = fmaf(a.w, w3.z, acc[e][2]);
                acc[e][3] = fmaf(a.x, w0.w, acc[e][3]);
                acc[e][3] = fmaf(a.y, w1.w, acc[e][3]);
                acc[e][3] = fmaf(a.z, w2.w, acc[e][3]);
                acc[e][3] = fmaf(a.w, w3.w, acc[e][3]);
            }
        }
        #pragma unroll
        for (int e = 0; e < 4; ++e) {
            float4 r;
            r.x = gelu_exact(acc[e][0]);
            r.y = gelu_exact(acc[e][1]);
            r.z = gelu_exact(acc[e][2]);
            r.w = gelu_exact(acc[e][3]);
            *(float4*)&s_h2[e0 + e][j0] = r;
        }
    }
    __syncthreads();

    // ---- stage 3: k3 = h2 @ W3 + b3 ; msg = wq*k3*f ; segment reduce ----
    {
        const int jg = t & 15;      // j0 = jg*4 (covers 64 cols)
        const int e  = t >> 4;      // 0..31, one edge per thread-group
        const int j0 = jg * 4;
        float acc[4];
        float4 bv = *(const float4*)&b3[j0];
        acc[0] = bv.x; acc[1] = bv.y; acc[2] = bv.z; acc[3] = bv.w;
        for (int k = 0; k < DH; k += 4) {
            float4 a  = *(const float4*)&s_h2[e][k];
            float4 w0 = *(const float4*)&W3[(k + 0) * DC + j0];
            float4 w1 = *(const float4*)&W3[(k + 1) * DC + j0];
            float4 w2 = *(const float4*)&W3[(k + 2) * DC + j0];
            float4 w3 = *(const float4*)&W3[(k + 3) * DC + j0];
            acc[0] = fmaf(a.x, w0.x, acc[0]);
            acc[0] = fmaf(a.y, w1.x, acc[0]);
            acc[0] = fmaf(a.z, w2.x, acc[0]);
            acc[0] = fmaf(a.w, w3.x, acc[0]);
            acc[1] = fmaf(a.x, w0.y, acc[1]);
            acc[1] = fmaf(a.y, w1.y, acc[1]);
            acc[1] = fmaf(a.z, w2.y, acc[1]);
            acc[1] = fmaf(a.w, w3.y, acc[1]);
            acc[2] = fmaf(a.x, w0.z, acc[2]);
            acc[2] = fmaf(a.y, w1.z, acc[2]);
            acc[2] = fmaf(a.z, w2.z, acc[2]);
            acc[2] = fmaf(a.w, w3.z, acc[2]);
            acc[3] = fmaf(a.x, w0.w, acc[3]);
            acc[3] = fmaf(a.y, w1.w, acc[3]);
            acc[3] = fmaf(a.z, w2.w, acc[3]);
            acc[3] = fmaf(a.w, w3.w, acc[3]);
        }
        // msg = weights[nbr] * k3 * f_y[nbr]  (f values live in agg cols 6..69)
        float wgt = s_wq[e];
        float p[4];
        #pragma unroll
        for (int q = 0; q < 4; ++q)
            p[q] = wgt * acc[q] * su.agg[e][6 + j0 + q];

        __syncthreads();            // all agg reads done before red overwrites it
        float4 pv; pv.x = p[0]; pv.y = p[1]; pv.z = p[2]; pv.w = p[3];
        *(float4*)&su.red[e][j0] = pv;
        __syncthreads();

        if (t < DC) {
            float s = 0.f;
            #pragma unroll
            for (int g = 0; g < DEG; ++g) s += su.red[g][t];
            out[i * DC + t] = s;
        }
    }
}

extern "C" void kernel_launch(void* const* d_in, const int* in_sizes, int n_in,
                              void* d_out, int out_size, void* d_ws, size_t ws_size,
                              hipStream_t stream) {
    const float* y   = (const float*)d_in[0];
    const float* x   = (const float*)d_in[1];
    const float* f_y = (const float*)d_in[2];
    const float* wq  = (const float*)d_in[3];
    const int*   nbr = (const int*)d_in[4];
    // d_in[5] = neighbors_row_splits (uniform arange*DEG, unused)
    const float* W1  = (const float*)d_in[6];
    const float* b1  = (const float*)d_in[7];
    const float* W2  = (const float*)d_in[8];
    const float* b2  = (const float*)d_in[9];
    const float* W3  = (const float*)d_in[10];
    const float* b3  = (const float*)d_in[11];
    float* out = (float*)d_out;

    hipLaunchKernelGGL(it_fused_kernel, dim3(NN), dim3(NT), 0, stream,
                       y, x, f_y, wq, nbr, W1, b1, W2, b2, W3, b3, out);
}

// Round 2
// 526.726 us; speedup vs baseline: 5.2955x; 5.2955x over previous
//
#include <hip/hip_runtime.h>
#include <math.h>
#include <stdint.h>

// Problem constants (fixed by setup_inputs)
#define NN   20000   // nodes
#define DEG  32      // neighbors per node
#define DIN  70      // 2*3 + 64 concat features
#define KP   96      // DIN padded to multiple of 32 for MFMA K
#define DH   256     // hidden
#define DC   64      // channels
#define NT   512     // threads per block (8 waves)
#define ET   128     // edges per block
#define NPB  4       // nodes per block (ET/DEG)

typedef _Float16 f16;
typedef _Float16 f16x8 __attribute__((ext_vector_type(8)));
typedef float    f32x4 __attribute__((ext_vector_type(4)));

// LDS pitches in f16 elements (odd-ish dword pitch -> spread banks; 16B aligned)
#define AGG_P 104     // 96 + 8   (52 dwords/row, 208 B)
#define H_P   264     // 256 + 8  (66 dwords/row, 528 B)

// f16 workspace layout (element offsets)
#define W1T_OFF 0
#define W2T_OFF (256*KP)                 // 24576
#define W3T_OFF (256*KP + 256*DH)        // 90112
#define WS_F16_TOTAL (256*KP + 256*DH + DC*DH)   // 106496 f16 = 208 KB

__device__ __forceinline__ float gelu_fast(float v) {
    // exact (non-tanh) gelu via Abramowitz-Stegun 7.1.26 erf, |erf err| < 1.5e-7,
    // single-path (no divergent branch, unlike ocml erff)
    float u  = v * 0.70710678118654752f;
    float a  = fabsf(u);
    float t  = __builtin_amdgcn_rcpf(fmaf(0.3275911f, a, 1.0f));
    float p  = fmaf(1.061405429f, t, -1.453152027f);
    p = fmaf(p, t, 1.421413741f);
    p = fmaf(p, t, -0.284496736f);
    p = fmaf(p, t, 0.254829592f);
    p = p * t;
    float e  = __expf(-u * u);
    float er = fmaf(-p, e, 1.0f);          // erf(|u|)
    er = copysignf(er, u);
    return 0.5f * v * (1.0f + er);
}

__device__ __forceinline__ uint32_t pack2h(float a, float b) {
    f16 lo = (f16)a, hi = (f16)b;
    return (uint32_t)__builtin_bit_cast(uint16_t, lo)
         | ((uint32_t)__builtin_bit_cast(uint16_t, hi) << 16);
}

// ---- pre-kernel: fp32 weights -> transposed f16 in workspace ----
// w1t[n][k] (KP pitch, zero-padded k>=70), w2t[n][k], w3t[n][k]
__global__ void prep_weights(const float* __restrict__ W1,
                             const float* __restrict__ W2,
                             const float* __restrict__ W3,
                             f16* __restrict__ ws)
{
    int t = blockIdx.x * blockDim.x + threadIdx.x;
    if (t < W2T_OFF) {                       // w1t: [256][96]
        int n = t / KP, k = t - n * KP;
        ws[t] = (k < DIN) ? (f16)W1[k * DH + n] : (f16)0.0f;
    } else if (t < W3T_OFF) {                // w2t: [256][256]
        int u = t - W2T_OFF;
        int n = u >> 8, k = u & 255;
        ws[t] = (f16)W2[k * DH + n];
    } else if (t < WS_F16_TOTAL) {           // w3t: [64][256]
        int u = t - W3T_OFF;
        int n = u >> 8, k = u & 255;
        ws[t] = (f16)W3[k * DC + n];
    }
}

// ---- main fused kernel ----
__global__ __launch_bounds__(NT, 2)
void it_mfma_kernel(const float* __restrict__ y,
                    const float* __restrict__ x,
                    const float* __restrict__ f_y,
                    const float* __restrict__ wq,
                    const int*   __restrict__ nbr,
                    const float* __restrict__ b1,
                    const float* __restrict__ b2,
                    const float* __restrict__ b3,
                    const f16*  __restrict__ ws,
                    float* __restrict__ out)
{
    const int blk  = blockIdx.x;
    const int t    = threadIdx.x;
    const int lane = t & 63;
    const int w    = t >> 6;        // wave 0..7
    const int l15  = lane & 15;
    const int lk   = lane >> 4;     // 0..3

    const f16* w1t = ws + W1T_OFF;
    const f16* w2t = ws + W2T_OFF;
    const f16* w3t = ws + W3T_OFF;

    __shared__ __align__(16) f16 s_agg[ET][AGG_P];   // 26 KB, f16 agg (holds f for the end)
    __shared__ __align__(16) f16 s_h[ET][H_P];       // 66 KB, h1 then h2
    __shared__ int   s_nbr[ET];
    __shared__ float s_wq[ET];
    __shared__ float s_red[8][DC];                   // per-wave partials

    // ---- phase A: neighbor ids + quadrature weights ----
    if (t < ET) {
        int n = nbr[blk * ET + t];
        s_nbr[t] = n;
        s_wq[t]  = wq[n];
    }
    __syncthreads();

    // ---- phase B: gather agg = concat(y[nbr], x[node], f[nbr]) as f16 ----
    {
        uint32_t* aggu = (uint32_t*)&s_agg[0][0];    // 52 dwords per row
        #pragma unroll
        for (int p = 0; p < 8; ++p) {                // f part: dword cols 3..34
            int idx = t + p * NT;                    // 0..4095
            int e   = idx >> 5;
            int c2  = idx & 31;                      // f float-pair index
            int n   = s_nbr[e];
            float2 fv = *(const float2*)&f_y[n * DC + 2 * c2];
            aggu[e * 52 + 3 + c2] = pack2h(fv.x, fv.y);
        }
        if (t < ET) {                                // y/x + zero pad
            int e = t;
            int n = s_nbr[e];
            int node = blk * NPB + (e >> 5);
            float y0 = y[n*3], y1 = y[n*3+1], y2 = y[n*3+2];
            float x0 = x[node*3], x1 = x[node*3+1], x2 = x[node*3+2];
            aggu[e*52 + 0] = pack2h(y0, y1);
            aggu[e*52 + 1] = pack2h(y2, x0);
            aggu[e*52 + 2] = pack2h(x1, x2);
            #pragma unroll
            for (int c = 35; c < 48; ++c) aggu[e*52 + c] = 0;  // k = 70..95 -> 0
        }
    }
    __syncthreads();

    // wave partition for GEMM1/2: 2 M-groups x 4 N-groups
    const int m_base = (w >> 2) * 64;    // 4 M-tiles: edges m_base..+63
    const int n_base = (w & 3) * 64;     // 4 N-tiles: cols  n_base..+63

    f32x4 acc[4][4];

    // ---- stage 1: h1 = gelu(agg @ W1 + b1), K = 96 ----
    #pragma unroll
    for (int nj = 0; nj < 4; ++nj) {
        float bv = b1[n_base + nj*16 + l15];
        #pragma unroll
        for (int mi = 0; mi < 4; ++mi) acc[mi][nj] = (f32x4){bv, bv, bv, bv};
    }
    #pragma unroll
    for (int ks = 0; ks < KP/32; ++ks) {
        const int k0 = ks*32 + lk*8;
        f16x8 a[4], b[4];
        #pragma unroll
        for (int mi = 0; mi < 4; ++mi)
            a[mi] = *(const f16x8*)&s_agg[m_base + mi*16 + l15][k0];
        #pragma unroll
        for (int nj = 0; nj < 4; ++nj)
            b[nj] = *(const f16x8*)&w1t[(n_base + nj*16 + l15) * KP + k0];
        #pragma unroll
        for (int mi = 0; mi < 4; ++mi)
            #pragma unroll
            for (int nj = 0; nj < 4; ++nj)
                acc[mi][nj] = __builtin_amdgcn_mfma_f32_16x16x32_f16(a[mi], b[nj], acc[mi][nj], 0, 0, 0);
    }
    // gelu + store h1 (no sync needed: s_h not read yet this iteration)
    #pragma unroll
    for (int mi = 0; mi < 4; ++mi)
        #pragma unroll
        for (int nj = 0; nj < 4; ++nj)
            #pragma unroll
            for (int r = 0; r < 4; ++r)
                s_h[m_base + mi*16 + lk*4 + r][n_base + nj*16 + l15] =
                    (f16)gelu_fast(acc[mi][nj][r]);
    __syncthreads();

    // ---- stage 2: h2 = gelu(h1 @ W2 + b2), K = 256 ----
    #pragma unroll
    for (int nj = 0; nj < 4; ++nj) {
        float bv = b2[n_base + nj*16 + l15];
        #pragma unroll
        for (int mi = 0; mi < 4; ++mi) acc[mi][nj] = (f32x4){bv, bv, bv, bv};
    }
    #pragma unroll 2
    for (int ks = 0; ks < DH/32; ++ks) {
        const int k0 = ks*32 + lk*8;
        f16x8 a[4], b[4];
        #pragma unroll
        for (int mi = 0; mi < 4; ++mi)
            a[mi] = *(const f16x8*)&s_h[m_base + mi*16 + l15][k0];
        #pragma unroll
        for (int nj = 0; nj < 4; ++nj)
            b[nj] = *(const f16x8*)&w2t[(n_base + nj*16 + l15) * DH + k0];
        #pragma unroll
        for (int mi = 0; mi < 4; ++mi)
            #pragma unroll
            for (int nj = 0; nj < 4; ++nj)
                acc[mi][nj] = __builtin_amdgcn_mfma_f32_16x16x32_f16(a[mi], b[nj], acc[mi][nj], 0, 0, 0);
    }
    __syncthreads();   // all waves done READING h1 before overwrite
    #pragma unroll
    for (int mi = 0; mi < 4; ++mi)
        #pragma unroll
        for (int nj = 0; nj < 4; ++nj)
            #pragma unroll
            for (int r = 0; r < 4; ++r)
                s_h[m_base + mi*16 + lk*4 + r][n_base + nj*16 + l15] =
                    (f16)gelu_fast(acc[mi][nj][r]);
    __syncthreads();

    // ---- stage 3: k3 = h2 @ W3 + b3; msg = wq*k3*f; segment reduce ----
    // wave w owns M-tile w (edges 16w..16w+15), all 4 N-tiles (cols 0..63)
    {
        f32x4 acc3[4];
        #pragma unroll
        for (int nj = 0; nj < 4; ++nj) {
            float bv = b3[nj*16 + l15];
            acc3[nj] = (f32x4){bv, bv, bv, bv};
        }
        #pragma unroll 2
        for (int ks = 0; ks < DH/32; ++ks) {
            const int k0 = ks*32 + lk*8;
            f16x8 a = *(const f16x8*)&s_h[w*16 + l15][k0];
            #pragma unroll
            for (int nj = 0; nj < 4; ++nj) {
                f16x8 b = *(const f16x8*)&w3t[(nj*16 + l15) * DH + k0];
                acc3[nj] = __builtin_amdgcn_mfma_f32_16x16x32_f16(a, b, acc3[nj], 0, 0, 0);
            }
        }
        // msg + in-lane partial over this lane's 4 rows
        float part[4];
        #pragma unroll
        for (int nj = 0; nj < 4; ++nj) {
            int c = nj*16 + l15;
            float s = 0.f;
            #pragma unroll
            for (int r = 0; r < 4; ++r) {
                int e = w*16 + lk*4 + r;                  // local edge
                float fv = (float)s_agg[e][6 + c];        // f(y) value (f16)
                s = fmaf(s_wq[e] * acc3[nj][r], fv, s);
            }
            part[nj] = s;
        }
        // butterfly over the 4 lane-groups (rows of the M-tile)
        #pragma unroll
        for (int nj = 0; nj < 4; ++nj) {
            part[nj] += __shfl_xor(part[nj], 16, 64);
            part[nj] += __shfl_xor(part[nj], 32, 64);
        }
        if (lane < 16) {
            #pragma unroll
            for (int nj = 0; nj < 4; ++nj) s_red[w][nj*16 + l15] = part[nj];
        }
    }
    __syncthreads();

    // combine the 2 wave-partials per node, write out
    if (t < NPB * DC) {
        int node = t >> 6, c = t & 63;
        out[(blk * NPB + node) * DC + c] = s_red[2*node][c] + s_red[2*node + 1][c];
    }
}

extern "C" void kernel_launch(void* const* d_in, const int* in_sizes, int n_in,
                              void* d_out, int out_size, void* d_ws, size_t ws_size,
                              hipStream_t stream) {
    const float* y   = (const float*)d_in[0];
    const float* x   = (const float*)d_in[1];
    const float* f_y = (const float*)d_in[2];
    const float* wq  = (const float*)d_in[3];
    const int*   nbr = (const int*)d_in[4];
    // d_in[5] = neighbors_row_splits (uniform arange*DEG, unused)
    const float* W1  = (const float*)d_in[6];
    const float* b1  = (const float*)d_in[7];
    const float* W2  = (const float*)d_in[8];
    const float* b2  = (const float*)d_in[9];
    const float* W3  = (const float*)d_in[10];
    const float* b3  = (const float*)d_in[11];
    float* out = (float*)d_out;
    f16*   ws  = (f16*)d_ws;

    hipLaunchKernelGGL(prep_weights, dim3((WS_F16_TOTAL + 255) / 256), dim3(256), 0, stream,
                       W1, W2, W3, ws);
    hipLaunchKernelGGL(it_mfma_kernel, dim3(NN / NPB), dim3(NT), 0, stream,
                       y, x, f_y, wq, nbr, b1, b2, b3, ws, out);
}

// Round 3
// 381.928 us; speedup vs baseline: 7.3032x; 1.3791x over previous
//
#include <hip/hip_runtime.h>
#include <math.h>
#include <stdint.h>

// Problem constants (fixed by setup_inputs)
#define NN   20000   // nodes
#define DEG  32      // neighbors per node
#define DIN  70      // 2*3 + 64 concat features
#define KP   96      // DIN padded to multiple of 32 for MFMA K
#define DH   256     // hidden
#define DC   64      // channels
#define NT   512     // threads per block (8 waves)
#define ET   128     // edges per block
#define NPB  4       // nodes per block (ET/DEG)

typedef _Float16 f16;
typedef _Float16 f16x4 __attribute__((ext_vector_type(4)));
typedef _Float16 f16x8 __attribute__((ext_vector_type(8)));
typedef float    f32x4 __attribute__((ext_vector_type(4)));

// LDS pitches in f16 elements (16B-aligned rows)
#define AGG_P 104     // 96 + 8
#define H_P   264     // 256 + 8

// f16 workspace layout (element offsets)
#define W1T_OFF 0
#define W2T_OFF (256*KP)
#define W3T_OFF (256*KP + 256*DH)
#define WS_F16_TOTAL (256*KP + 256*DH + DC*DH)

__device__ __forceinline__ float gelu_fast(float v) {
    // exact (non-tanh) gelu via Abramowitz-Stegun 7.1.26 erf, |erf err| < 1.5e-7
    float u  = v * 0.70710678118654752f;
    float a  = fabsf(u);
    float t  = __builtin_amdgcn_rcpf(fmaf(0.3275911f, a, 1.0f));
    float p  = fmaf(1.061405429f, t, -1.453152027f);
    p = fmaf(p, t, 1.421413741f);
    p = fmaf(p, t, -0.284496736f);
    p = fmaf(p, t, 0.254829592f);
    p = p * t;
    float e  = __expf(-u * u);
    float er = fmaf(-p, e, 1.0f);          // erf(|u|)
    er = copysignf(er, u);
    return 0.5f * v * (1.0f + er);
}

__device__ __forceinline__ uint32_t pack2h(float a, float b) {
    f16 lo = (f16)a, hi = (f16)b;
    return (uint32_t)__builtin_bit_cast(uint16_t, lo)
         | ((uint32_t)__builtin_bit_cast(uint16_t, hi) << 16);
}

// ---- pre-kernel: fp32 weights -> transposed f16 in workspace ----
__global__ void prep_weights(const float* __restrict__ W1,
                             const float* __restrict__ W2,
                             const float* __restrict__ W3,
                             f16* __restrict__ ws)
{
    int t = blockIdx.x * blockDim.x + threadIdx.x;
    if (t < W2T_OFF) {                       // w1t: [256][96]
        int n = t / KP, k = t - n * KP;
        ws[t] = (k < DIN) ? (f16)W1[k * DH + n] : (f16)0.0f;
    } else if (t < W3T_OFF) {                // w2t: [256][256]
        int u = t - W2T_OFF;
        int n = u >> 8, k = u & 255;
        ws[t] = (f16)W2[k * DH + n];
    } else if (t < WS_F16_TOTAL) {           // w3t: [64][256]
        int u = t - W3T_OFF;
        int n = u >> 8, k = u & 255;
        ws[t] = (f16)W3[k * DC + n];
    }
}

// ---- main fused kernel ----
__global__ __launch_bounds__(NT, 4)
void it_mfma_kernel(const float* __restrict__ y,
                    const float* __restrict__ x,
                    const float* __restrict__ f_y,
                    const float* __restrict__ wq,
                    const int*   __restrict__ nbr,
                    const float* __restrict__ b1,
                    const float* __restrict__ b2,
                    const float* __restrict__ b3,
                    const f16*  __restrict__ ws,
                    float* __restrict__ out)
{
    const int blk  = blockIdx.x;
    const int t    = threadIdx.x;
    const int lane = t & 63;
    const int w    = t >> 6;        // wave 0..7
    const int l15  = lane & 15;
    const int lk   = lane >> 4;     // 0..3

    const f16* w1t = ws + W1T_OFF;
    const f16* w2t = ws + W2T_OFF;
    const f16* w3t = ws + W3T_OFF;

    // union: agg tile (26.6 KB) aliases h tile (67.6 KB); agg dead after stage-1 MFMA
    __shared__ __align__(16) unsigned char s_u[ET * H_P * 2];   // 67584 B
    f16 (*s_agg)[AGG_P] = (f16(*)[AGG_P])s_u;
    f16 (*s_h)[H_P]     = (f16(*)[H_P])s_u;
    __shared__ int   s_nbr[ET];
    __shared__ float s_wq[ET];
    __shared__ float s_red[8][DC];

    // ---- phase A: neighbor ids + quadrature weights ----
    if (t < ET) {
        int n = nbr[blk * ET + t];
        s_nbr[t] = n;
        s_wq[t]  = wq[n];
    }
    __syncthreads();

    // ---- phase B: gather agg = concat(y[nbr], x[node], f[nbr]) as f16 ----
    {
        uint32_t* aggu = (uint32_t*)&s_agg[0][0];    // 52 dwords per row
        #pragma unroll
        for (int p = 0; p < 8; ++p) {                // f part: dword cols 3..34
            int idx = t + p * NT;
            int e   = idx >> 5;
            int c2  = idx & 31;
            int n   = s_nbr[e];
            float2 fvv = *(const float2*)&f_y[n * DC + 2 * c2];
            aggu[e * 52 + 3 + c2] = pack2h(fvv.x, fvv.y);
        }
        if (t < ET) {
            int e = t;
            int n = s_nbr[e];
            int node = blk * NPB + (e >> 5);
            float y0 = y[n*3], y1 = y[n*3+1], y2 = y[n*3+2];
            float x0 = x[node*3], x1 = x[node*3+1], x2 = x[node*3+2];
            aggu[e*52 + 0] = pack2h(y0, y1);
            aggu[e*52 + 1] = pack2h(y2, x0);
            aggu[e*52 + 2] = pack2h(x1, x2);
            #pragma unroll
            for (int c = 35; c < 48; ++c) aggu[e*52 + c] = 0;
        }
    }
    __syncthreads();

    // wave partition for GEMM1/2: 2 M-groups x 4 N-groups
    const int m_base = (w >> 2) * 64;
    const int n_base = (w & 3) * 64;

    f32x4 acc[4][4];

    // ---- stage 1: h1 = gelu(agg @ W1 + b1), K = 96 (swapped mfma -> D=h^T) ----
    // D layout: lane col = edge (l15), rows = hidden n (lk*4+r)
    #pragma unroll
    for (int nj = 0; nj < 4; ++nj) {
        float4 bv = *(const float4*)&b1[n_base + nj*16 + lk*4];
        #pragma unroll
        for (int mi = 0; mi < 4; ++mi) acc[mi][nj] = (f32x4){bv.x, bv.y, bv.z, bv.w};
    }
    #pragma unroll
    for (int ks = 0; ks < KP/32; ++ks) {
        const int k0 = ks*32 + lk*8;
        f16x8 a[4], b[4];
        #pragma unroll
        for (int mi = 0; mi < 4; ++mi)
            a[mi] = *(const f16x8*)&s_agg[m_base + mi*16 + l15][k0];
        #pragma unroll
        for (int nj = 0; nj < 4; ++nj)
            b[nj] = *(const f16x8*)&w1t[(n_base + nj*16 + l15) * KP + k0];
        #pragma unroll
        for (int mi = 0; mi < 4; ++mi)
            #pragma unroll
            for (int nj = 0; nj < 4; ++nj)
                acc[mi][nj] = __builtin_amdgcn_mfma_f32_16x16x32_f16(b[nj], a[mi], acc[mi][nj], 0, 0, 0);
    }
    __syncthreads();   // ALL waves done reading s_agg before h1 overwrites the union
    #pragma unroll
    for (int mi = 0; mi < 4; ++mi)
        #pragma unroll
        for (int nj = 0; nj < 4; ++nj) {
            int e  = m_base + mi*16 + l15;
            int n0 = n_base + nj*16 + lk*4;
            f16x4 hv;
            #pragma unroll
            for (int r = 0; r < 4; ++r) hv[r] = (f16)gelu_fast(acc[mi][nj][r]);
            *(f16x4*)&s_h[e][n0] = hv;     // one ds_write_b64
        }
    __syncthreads();

    // ---- stage 2: h2 = gelu(h1 @ W2 + b2), K = 256 (swapped) ----
    #pragma unroll
    for (int nj = 0; nj < 4; ++nj) {
        float4 bv = *(const float4*)&b2[n_base + nj*16 + lk*4];
        #pragma unroll
        for (int mi = 0; mi < 4; ++mi) acc[mi][nj] = (f32x4){bv.x, bv.y, bv.z, bv.w};
    }
    #pragma unroll 2
    for (int ks = 0; ks < DH/32; ++ks) {
        const int k0 = ks*32 + lk*8;
        f16x8 a[4], b[4];
        #pragma unroll
        for (int mi = 0; mi < 4; ++mi)
            a[mi] = *(const f16x8*)&s_h[m_base + mi*16 + l15][k0];
        #pragma unroll
        for (int nj = 0; nj < 4; ++nj)
            b[nj] = *(const f16x8*)&w2t[(n_base + nj*16 + l15) * DH + k0];
        #pragma unroll
        for (int mi = 0; mi < 4; ++mi)
            #pragma unroll
            for (int nj = 0; nj < 4; ++nj)
                acc[mi][nj] = __builtin_amdgcn_mfma_f32_16x16x32_f16(b[nj], a[mi], acc[mi][nj], 0, 0, 0);
    }
    __syncthreads();   // all waves done reading h1 before overwrite
    #pragma unroll
    for (int mi = 0; mi < 4; ++mi)
        #pragma unroll
        for (int nj = 0; nj < 4; ++nj) {
            int e  = m_base + mi*16 + l15;
            int n0 = n_base + nj*16 + lk*4;
            f16x4 hv;
            #pragma unroll
            for (int r = 0; r < 4; ++r) hv[r] = (f16)gelu_fast(acc[mi][nj][r]);
            *(f16x4*)&s_h[e][n0] = hv;
        }
    __syncthreads();

    // ---- stage 3: k3 = h2 @ W3 + b3; msg = wq*k3*f; segment reduce ----
    // unswapped: lane col = c (l15 within nj tile), rows = edges (lk*4+r)
    {
        // preload f (fp32 from global, L2/L3-hot) and wq for this wave's edges
        float fv[4][4]; float wqe[4];
        #pragma unroll
        for (int r = 0; r < 4; ++r) {
            int e = w*16 + lk*4 + r;
            int n = s_nbr[e];
            wqe[r] = s_wq[e];
            #pragma unroll
            for (int nj = 0; nj < 4; ++nj)
                fv[r][nj] = f_y[n * DC + nj*16 + l15];
        }
        f32x4 acc3[4];
        #pragma unroll
        for (int nj = 0; nj < 4; ++nj) {
            float bv = b3[nj*16 + l15];
            acc3[nj] = (f32x4){bv, bv, bv, bv};
        }
        #pragma unroll 2
        for (int ks = 0; ks < DH/32; ++ks) {
            const int k0 = ks*32 + lk*8;
            f16x8 a = *(const f16x8*)&s_h[w*16 + l15][k0];
            #pragma unroll
            for (int nj = 0; nj < 4; ++nj) {
                f16x8 b = *(const f16x8*)&w3t[(nj*16 + l15) * DH + k0];
                acc3[nj] = __builtin_amdgcn_mfma_f32_16x16x32_f16(a, b, acc3[nj], 0, 0, 0);
            }
        }
        float part[4];
        #pragma unroll
        for (int nj = 0; nj < 4; ++nj) {
            float s = 0.f;
            #pragma unroll
            for (int r = 0; r < 4; ++r)
                s = fmaf(wqe[r] * acc3[nj][r], fv[r][nj], s);
            part[nj] = s;
        }
        #pragma unroll
        for (int nj = 0; nj < 4; ++nj) {
            part[nj] += __shfl_xor(part[nj], 16, 64);
            part[nj] += __shfl_xor(part[nj], 32, 64);
        }
        if (lane < 16) {
            #pragma unroll
            for (int nj = 0; nj < 4; ++nj) s_red[w][nj*16 + l15] = part[nj];
        }
    }
    __syncthreads();

    if (t < NPB * DC) {
        int node = t >> 6, c = t & 63;
        out[(blk * NPB + node) * DC + c] = s_red[2*node][c] + s_red[2*node + 1][c];
    }
}

extern "C" void kernel_launch(void* const* d_in, const int* in_sizes, int n_in,
                              void* d_out, int out_size, void* d_ws, size_t ws_size,
                              hipStream_t stream) {
    const float* y   = (const float*)d_in[0];
    const float* x   = (const float*)d_in[1];
    const float* f_y = (const float*)d_in[2];
    const float* wq  = (const float*)d_in[3];
    const int*   nbr = (const int*)d_in[4];
    const float* W1  = (const float*)d_in[6];
    const float* b1  = (const float*)d_in[7];
    const float* W2  = (const float*)d_in[8];
    const float* b2  = (const float*)d_in[9];
    const float* W3  = (const float*)d_in[10];
    const float* b3  = (const float*)d_in[11];
    float* out = (float*)d_out;
    f16*   ws  = (f16*)d_ws;

    hipLaunchKernelGGL(prep_weights, dim3((WS_F16_TOTAL + 255) / 256), dim3(256), 0, stream,
                       W1, W2, W3, ws);
    hipLaunchKernelGGL(it_mfma_kernel, dim3(NN / NPB), dim3(NT), 0, stream,
                       y, x, f_y, wq, nbr, b1, b2, b3, ws, out);
}